// Round 1
// baseline (222.921 us; speedup 1.0000x reference)
//
#include <hip/hip_runtime.h>
#include <hip/hip_bf16.h>

typedef unsigned short u16;
typedef u16 u16x4 __attribute__((ext_vector_type(4)));
typedef u16 u16x8 __attribute__((ext_vector_type(8)));
typedef __bf16 bf16x8 __attribute__((ext_vector_type(8)));
typedef float f32x4 __attribute__((ext_vector_type(4)));

__device__ __forceinline__ u16 f2bf(float f) {
  unsigned u = __float_as_uint(f);
  u += 0x7FFFu + ((u >> 16) & 1u);   // round-to-nearest-even
  return (u16)(u >> 16);
}
__device__ __forceinline__ float bf2f(u16 h) {
  return __uint_as_float(((unsigned)h) << 16);
}
__device__ __forceinline__ float tanh_fast(float x) {
  float t = __expf(2.0f * x);
  return 1.0f - 2.0f / (t + 1.0f);
}
__device__ __forceinline__ float sigmoid_fast(float x) {
  return 1.0f / (1.0f + __expf(-x));
}

// async global->LDS, 16B per lane. LDS dest semantics: wave-uniform base +
// lane*16 (m104/m108) — our per-lane LDS pointers are linear in tid, so lane0
// holds the wave base and the mapping matches exactly. LDS must be UNPADDED.
__device__ __forceinline__ void glds16(const u16* g, u16* l) {
  __builtin_amdgcn_global_load_lds(
      (const __attribute__((address_space(1))) unsigned int*)g,
      (__attribute__((address_space(3))) unsigned int*)l, 16, 0, 0);
}

// ---------------- fused prep: fp32->bf16 casts + attn weight-diff + zero v ----------------
__device__ __forceinline__ void cvt4(const float* __restrict__ s, u16* __restrict__ d, int q) {
  float4 v = ((const float4*)s)[q];
  u16x4 o = { f2bf(v.x), f2bf(v.y), f2bf(v.z), f2bf(v.w) };
  ((u16x4*)d)[q] = o;
}

__global__ __launch_bounds__(256)
void prep_kernel(const float* __restrict__ obs, const float* __restrict__ We,
                 const float* __restrict__ W1, const float* __restrict__ W2,
                 const float* __restrict__ aW, const float* __restrict__ ab,
                 u16* __restrict__ obs_b, u16* __restrict__ We_b,
                 u16* __restrict__ W1_b, u16* __restrict__ W2_b,
                 u16* __restrict__ Wd, float* __restrict__ bd,
                 float* __restrict__ vzero) {
  int q = blockIdx.x * 256 + threadIdx.x;          // quad (4-element) index
  if (q < 1024) ((float4*)vzero)[q] = (float4){0.f, 0.f, 0.f, 0.f};  // zero v[4096]
  if (q < 1048576) { cvt4(obs, obs_b, q); return; }                 // 4096*1024
  q -= 1048576;
  if (q < 131072) { cvt4(We, We_b, q); return; }                    // 512*1024
  q -= 131072;
  if (q < 524288) { cvt4(W1, W1_b, q); return; }                    // 2048*1024
  q -= 524288;
  if (q < 1048576) { cvt4(W2, W2_b, q); return; }                   // 2048*2048
  q -= 1048576;
  if (q < 131072) {                                                  // Wd: 1024*512
    int i0 = q * 4;
    int o = i0 >> 9, e0 = i0 & 511;
    const float* p = aW + (size_t)o * 1024 + e0 * 2;
    float4 v0 = *(const float4*)p;
    float4 v1 = *(const float4*)(p + 4);
    u16x4 od = { f2bf(v0.y - v0.x), f2bf(v0.w - v0.z),
                 f2bf(v1.y - v1.x), f2bf(v1.w - v1.z) };
    *(u16x4*)(Wd + i0) = od;
    if (q < 256) {                                                   // bd: 1024
      float4 a0 = *(const float4*)(ab + q * 8);
      float4 a1 = *(const float4*)(ab + q * 8 + 4);
      float4 ob = { a0.y - a0.x, a0.w - a0.z, a1.y - a1.x, a1.w - a1.z };
      *(float4*)(bd + q * 4) = ob;
    }
  }
}

// ---------------- bf16 MFMA GEMM, C = A[M,K] * Bt[N,K]^T, BK=64 ----------------
// m97-structure staging: global_load_lds direct-to-LDS (no VGPR round-trip, no
// ds_write). LDS linear (stride 64 — glds requires wave-uniform-base+lane*16
// dest; padding would corrupt). 2 barriers per K-step; overlap across the
// 4-5 resident blocks/CU hides the vmcnt(0) drain (m151: 874 vs 646 TF
// reg-staged at this exact tile).
// EP 0: outb = bf16(tanh(x + bias[col]))
// EP 1: att = sigmoid(x + bias[col]); outf = att; sa = bf16(obs_b * att)
// EP 2: fused v-dot: atomicAdd(vout[row], sum_col tanh(x+bias)*W3[col]) — no C store
template <int BM, int BN, int EP>
__global__ __launch_bounds__(256, 4)
void gemm_bt(const u16* __restrict__ A, const u16* __restrict__ Bt,
             int N, int K,
             const float* __restrict__ bias,
             u16* __restrict__ outb, float* __restrict__ outf,
             const u16* __restrict__ obsb, u16* __restrict__ sa,
             const float* __restrict__ W3, const float* __restrict__ b3,
             float* __restrict__ vout) {
  constexpr int CA = BM / 32;          // staging passes (32 rows per pass)
  constexpr int CB = BN / 32;
  constexpr int MI = BM / 32;          // 16-row frags per wave
  constexpr int NJ = BN / 32;          // 16-col frags per wave

  __shared__ __align__(16) u16 As[BM * 64];
  __shared__ __align__(16) u16 Bs[BN * 64];

  const int tid = threadIdx.x;
  const int lane = tid & 63;
  const int wave = tid >> 6;
  const int bm = blockIdx.x, bn = blockIdx.y;

  const int r0 = tid >> 3;             // staging row 0..31
  const int kc = (tid & 7) * 8;        // element offset in 64-wide K slab

  const u16* gA = A + (size_t)(bm * BM + r0) * K + kc;
  const u16* gB = Bt + (size_t)(bn * BN + r0) * K + kc;
  u16* lA = As + r0 * 64 + kc;         // == As + tid*8: linear in tid
  u16* lB = Bs + r0 * 64 + kc;

  const int wm = (wave >> 1) * (BM / 2);
  const int wn = (wave & 1) * (BN / 2);
  const int fr = lane & 15;
  const int koff = (lane >> 4) * 8;

  f32x4 acc[MI][NJ];
#pragma unroll
  for (int i = 0; i < MI; ++i)
#pragma unroll
    for (int j = 0; j < NJ; ++j)
      acc[i][j] = (f32x4){0.f, 0.f, 0.f, 0.f};

  const int T = K >> 6;
  for (int k = 0; k < T; ++k) {
    if (k) __syncthreads();            // prev tile's LDS readers done
#pragma unroll
    for (int q = 0; q < CA; ++q)
      glds16(gA + (size_t)q * 32 * K, lA + q * 32 * 64);
#pragma unroll
    for (int q = 0; q < CB; ++q)
      glds16(gB + (size_t)q * 32 * K, lB + q * 32 * 64);
    gA += 64; gB += 64;
    __syncthreads();                   // vmcnt(0) drain + barrier: tile ready

#pragma unroll
    for (int s = 0; s < 2; ++s) {      // two K=32 sub-steps per staged slab
      bf16x8 a[MI], b[NJ];
#pragma unroll
      for (int i = 0; i < MI; ++i)
        a[i] = *(const bf16x8*)(As + (wm + i * 16 + fr) * 64 + s * 32 + koff);
#pragma unroll
      for (int j = 0; j < NJ; ++j)
        b[j] = *(const bf16x8*)(Bs + (wn + j * 16 + fr) * 64 + s * 32 + koff);
#pragma unroll
      for (int i = 0; i < MI; ++i)
#pragma unroll
        for (int j = 0; j < NJ; ++j)
          acc[i][j] = __builtin_amdgcn_mfma_f32_16x16x32_bf16(a[i], b[j], acc[i][j], 0, 0, 0);
    }
  }

  // epilogue: row = bm*BM + wm + i*16 + (lane>>4)*4 + r, col = bn*BN + wn + j*16 + fr
  if constexpr (EP == 2) {
    float vpart[MI][4];
#pragma unroll
    for (int i = 0; i < MI; ++i)
#pragma unroll
      for (int r = 0; r < 4; ++r) vpart[i][r] = 0.f;
#pragma unroll
    for (int j = 0; j < NJ; ++j) {
      const int col = bn * BN + wn + j * 16 + fr;
      const float bv = bias[col];
      const float w3 = W3[col];
#pragma unroll
      for (int i = 0; i < MI; ++i)
#pragma unroll
        for (int r = 0; r < 4; ++r)
          vpart[i][r] += tanh_fast(acc[i][j][r] + bv) * w3;
    }
    const bool lead = (fr == 0);
    const bool addb = (bn == 0) && ((wave & 1) == 0);
#pragma unroll
    for (int i = 0; i < MI; ++i)
#pragma unroll
      for (int r = 0; r < 4; ++r) {
        float p = vpart[i][r];
        p += __shfl_xor(p, 8);
        p += __shfl_xor(p, 4);
        p += __shfl_xor(p, 2);
        p += __shfl_xor(p, 1);
        if (lead) {
          const int row = bm * BM + wm + i * 16 + (lane >> 4) * 4 + r;
          atomicAdd(vout + row, addb ? p + b3[0] : p);
        }
      }
  } else {
#pragma unroll
    for (int j = 0; j < NJ; ++j) {
      const int col = bn * BN + wn + j * 16 + fr;
      const float bv = bias[col];
#pragma unroll
      for (int i = 0; i < MI; ++i) {
#pragma unroll
        for (int r = 0; r < 4; ++r) {
          const int row = bm * BM + wm + i * 16 + (lane >> 4) * 4 + r;
          const float x = acc[i][j][r] + bv;
          const size_t idx = (size_t)row * N + col;
          if constexpr (EP == 0) {
            outb[idx] = f2bf(tanh_fast(x));
          } else {
            const float att = sigmoid_fast(x);
            outf[idx] = att;
            sa[idx] = f2bf(bf2f(obsb[idx]) * att);
          }
        }
      }
    }
  }
}

extern "C" void kernel_launch(void* const* d_in, const int* in_sizes, int n_in,
                              void* d_out, int out_size, void* d_ws, size_t ws_size,
                              hipStream_t stream) {
  const float* obs   = (const float*)d_in[0];   // [4096,1024]
  const float* We    = (const float*)d_in[1];   // [512,1024]
  const float* be    = (const float*)d_in[2];   // [512]
  const float* attnW = (const float*)d_in[3];   // [1024,512,2]
  const float* attnb = (const float*)d_in[4];   // [1024,2]
  const float* W1    = (const float*)d_in[5];   // [2048,1024]
  const float* b1    = (const float*)d_in[6];   // [2048]
  const float* W2    = (const float*)d_in[7];   // [2048,2048]
  const float* b2    = (const float*)d_in[8];   // [2048]
  const float* W3    = (const float*)d_in[9];   // [1,2048]
  const float* b3    = (const float*)d_in[10];  // [1]
  float* out = (float*)d_out;                   // [4096] v, then [4096,1024] attention

  char* ws = (char*)d_ws;
  u16*   We_b  = (u16*)(ws + 0x00000000);   // 1 MB
  u16*   Wd_b  = (u16*)(ws + 0x00100000);   // 1 MB
  u16*   W1_b  = (u16*)(ws + 0x00200000);   // 4 MB
  u16*   W2_b  = (u16*)(ws + 0x00600000);   // 8 MB
  float* bd    = (float*)(ws + 0x00E00000); // 4 KB
  u16*   obs_b = (u16*)(ws + 0x00E01000);   // 8 MB
  u16*   e_b   = (u16*)(ws + 0x01601000);   // 4 MB
  u16*   sa_b  = (u16*)(ws + 0x01A01000);   // 8 MB
  u16*   h1_b  = (u16*)(ws + 0x02201000);   // 16 MB (end ~50 MB; h2 never stored)

  // prep: all casts + attn weight prep + zero v, one launch
  prep_kernel<<<11264, 256, 0, stream>>>(obs, We, W1, W2, attnW, attnb,
                                         obs_b, We_b, W1_b, W2_b, Wd_b, bd, out);

  // G1: e = tanh(obs @ We^T + be)   [4096,512]  64x64 -> 512 blocks
  gemm_bt<64, 64, 0><<<dim3(64, 8), 256, 0, stream>>>(
      obs_b, We_b, 512, 1024, be, e_b, nullptr, nullptr, nullptr, nullptr, nullptr, nullptr);
  // G2: att = sigmoid(e @ Wd^T + bd); sa = obs*att   [4096,1024]  128x64 -> 512 blocks
  gemm_bt<128, 64, 1><<<dim3(32, 16), 256, 0, stream>>>(
      e_b, Wd_b, 1024, 512, bd, nullptr, out + 4096, obs_b, sa_b, nullptr, nullptr, nullptr);
  // G3: h1 = tanh(sa @ W1^T + b1)   [4096,2048]  128x128 -> 512 blocks
  gemm_bt<128, 128, 0><<<dim3(32, 16), 256, 0, stream>>>(
      sa_b, W1_b, 2048, 1024, b1, h1_b, nullptr, nullptr, nullptr, nullptr, nullptr, nullptr);
  // G4+v: v = tanh(h1 @ W2^T + b2) @ W3 + b3 — fused, h2 never stored
  gemm_bt<128, 128, 2><<<dim3(32, 16), 256, 0, stream>>>(
      h1_b, W2_b, 2048, 2048, b2, nullptr, nullptr, nullptr, nullptr, W3, b3, out);
}

// Round 2
// 189.938 us; speedup vs baseline: 1.1737x; 1.1737x over previous
//
#include <hip/hip_runtime.h>
#include <hip/hip_bf16.h>

typedef unsigned short u16;
typedef u16 u16x4 __attribute__((ext_vector_type(4)));
typedef u16 u16x8 __attribute__((ext_vector_type(8)));
typedef __bf16 bf16x8 __attribute__((ext_vector_type(8)));
typedef float f32x4 __attribute__((ext_vector_type(4)));

__device__ __forceinline__ u16 f2bf(float f) {
  unsigned u = __float_as_uint(f);
  u += 0x7FFFu + ((u >> 16) & 1u);   // round-to-nearest-even
  return (u16)(u >> 16);
}
__device__ __forceinline__ float bf2f(u16 h) {
  return __uint_as_float(((unsigned)h) << 16);
}
__device__ __forceinline__ float tanh_fast(float x) {
  float t = __expf(2.0f * x);
  return 1.0f - 2.0f / (t + 1.0f);
}
__device__ __forceinline__ float sigmoid_fast(float x) {
  return 1.0f / (1.0f + __expf(-x));
}

// async global->LDS, 16B per lane. Dest is wave-uniform base + lane*16; our
// per-lane dest (= base + tid*8 elems) is linear in tid, matching exactly.
__device__ __forceinline__ void glds16(const u16* g, u16* l) {
  __builtin_amdgcn_global_load_lds(
      (const __attribute__((address_space(1))) unsigned int*)g,
      (__attribute__((address_space(3))) unsigned int*)l, 16, 0, 0);
}

// ---------------- fused prep: fp32->bf16 casts + attn weight-diff + zero v ----------------
__device__ __forceinline__ void cvt4(const float* __restrict__ s, u16* __restrict__ d, int q) {
  float4 v = ((const float4*)s)[q];
  u16x4 o = { f2bf(v.x), f2bf(v.y), f2bf(v.z), f2bf(v.w) };
  ((u16x4*)d)[q] = o;
}

__global__ __launch_bounds__(256)
void prep_kernel(const float* __restrict__ obs, const float* __restrict__ We,
                 const float* __restrict__ W1, const float* __restrict__ W2,
                 const float* __restrict__ aW, const float* __restrict__ ab,
                 u16* __restrict__ obs_b, u16* __restrict__ We_b,
                 u16* __restrict__ W1_b, u16* __restrict__ W2_b,
                 u16* __restrict__ Wd, float* __restrict__ bd,
                 float* __restrict__ vzero) {
  int q = blockIdx.x * 256 + threadIdx.x;          // quad (4-element) index
  if (q < 1024) ((float4*)vzero)[q] = (float4){0.f, 0.f, 0.f, 0.f};  // zero v[4096]
  if (q < 1048576) { cvt4(obs, obs_b, q); return; }                 // 4096*1024
  q -= 1048576;
  if (q < 131072) { cvt4(We, We_b, q); return; }                    // 512*1024
  q -= 131072;
  if (q < 524288) { cvt4(W1, W1_b, q); return; }                    // 2048*1024
  q -= 524288;
  if (q < 1048576) { cvt4(W2, W2_b, q); return; }                   // 2048*2048
  q -= 1048576;
  if (q < 131072) {                                                  // Wd: 1024*512
    int i0 = q * 4;
    int o = i0 >> 9, e0 = i0 & 511;
    const float* p = aW + (size_t)o * 1024 + e0 * 2;
    float4 v0 = *(const float4*)p;
    float4 v1 = *(const float4*)(p + 4);
    u16x4 od = { f2bf(v0.y - v0.x), f2bf(v0.w - v0.z),
                 f2bf(v1.y - v1.x), f2bf(v1.w - v1.z) };
    *(u16x4*)(Wd + i0) = od;
    if (q < 256) {                                                   // bd: 1024
      float4 a0 = *(const float4*)(ab + q * 8);
      float4 a1 = *(const float4*)(ab + q * 8 + 4);
      float4 ob = { a0.y - a0.x, a0.w - a0.z, a1.y - a1.x, a1.w - a1.z };
      *(float4*)(bd + q * 4) = ob;
    }
  }
}

// ---------------- bf16 MFMA GEMM, C = A[M,K] * Bt[N,K]^T, BK=64 ----------------
// T3 "minimum 2-phase" dbuf: STAGE(buf^1 via glds) issued BEFORE compute(buf);
// one vmcnt(0)+barrier (= __syncthreads) per K-step. Loads for tile k+1 fly
// across tile k's 32 MFMAs -> within-block overlap (grid is 2 blocks/CU, so
// cross-block overlap alone is insufficient - r1 lesson). Buffers statically
// named (As0/As1) so alias analysis doesn't serialize glds vs ds_read.
// Bank-conflict fix without padding (glds needs linear dest): both-sides
// swizzle - global source chunk pre-XORed with row&7, fragment reads XOR the
// 16B-chunk index with fr&7. 16-way -> 2-way (free).
// EP 0: outb = bf16(tanh(x + bias[col]))
// EP 1: att = sigmoid(x + bias[col]); outf = att; sa = bf16(obs_b * att)
// EP 2: fused v-dot: atomicAdd(vout[row], sum_col tanh(x+bias)*W3[col]) — no C store
template <int BM, int BN, int EP>
__global__ __launch_bounds__(256, 2)
void gemm_bt(const u16* __restrict__ A, const u16* __restrict__ Bt,
             int N, int K,
             const float* __restrict__ bias,
             u16* __restrict__ outb, float* __restrict__ outf,
             const u16* __restrict__ obsb, u16* __restrict__ sa,
             const float* __restrict__ W3, const float* __restrict__ b3,
             float* __restrict__ vout) {
  constexpr int CA = BM / 32;          // staging passes (32 rows per pass)
  constexpr int CB = BN / 32;
  constexpr int MI = BM / 32;          // 16-row frags per wave
  constexpr int NJ = BN / 32;          // 16-col frags per wave

  __shared__ __align__(16) u16 As0[BM * 64];
  __shared__ __align__(16) u16 Bs0[BN * 64];
  __shared__ __align__(16) u16 As1[BM * 64];
  __shared__ __align__(16) u16 Bs1[BN * 64];

  const int tid = threadIdx.x;
  const int lane = tid & 63;
  const int wave = tid >> 6;
  const int bm = blockIdx.x, bn = blockIdx.y;

  const int r0 = tid >> 3;             // staging row 0..31
  // source chunk pre-swizzled: LDS slot (tid&7) of row r0 receives global
  // chunk (tid&7)^(r0&7); fragment reads undo the XOR.
  const int kcs = ((tid & 7) ^ (r0 & 7)) * 8;

  const u16* gA = A + (size_t)(bm * BM + r0) * K + kcs;
  const u16* gB = Bt + (size_t)(bn * BN + r0) * K + kcs;

  const int wm = (wave >> 1) * (BM / 2);
  const int wn = (wave & 1) * (BN / 2);
  const int fr = lane & 15;
  const int hi = lane >> 4;
  const int frx = fr & 7;              // read-side swizzle key (row&7 of all frag rows)

  f32x4 acc[MI][NJ];
#pragma unroll
  for (int i = 0; i < MI; ++i)
#pragma unroll
    for (int j = 0; j < NJ; ++j)
      acc[i][j] = (f32x4){0.f, 0.f, 0.f, 0.f};

  auto stage = [&](u16* __restrict__ dA, u16* __restrict__ dB) {
#pragma unroll
    for (int q = 0; q < CA; ++q)
      glds16(gA + (size_t)q * 32 * K, dA + tid * 8 + q * 2048);
#pragma unroll
    for (int q = 0; q < CB; ++q)
      glds16(gB + (size_t)q * 32 * K, dB + tid * 8 + q * 2048);
    gA += 64; gB += 64;
  };

  auto compute = [&](const u16* sA, const u16* sB) {
#pragma unroll
    for (int s = 0; s < 2; ++s) {      // two K=32 sub-steps per staged slab
      const int ck = ((s * 4 + hi) ^ frx) * 8;   // swizzled 16B-chunk offset
      bf16x8 a[MI], b[NJ];
#pragma unroll
      for (int i = 0; i < MI; ++i)
        a[i] = *(const bf16x8*)(sA + (wm + i * 16 + fr) * 64 + ck);
#pragma unroll
      for (int j = 0; j < NJ; ++j)
        b[j] = *(const bf16x8*)(sB + (wn + j * 16 + fr) * 64 + ck);
#pragma unroll
      for (int i = 0; i < MI; ++i)
#pragma unroll
        for (int j = 0; j < NJ; ++j)
          acc[i][j] = __builtin_amdgcn_mfma_f32_16x16x32_bf16(a[i], b[j], acc[i][j], 0, 0, 0);
    }
  };

  const int T = K >> 6;                // all call sites: T even
  stage(As0, Bs0);
  __syncthreads();                     // tile 0 ready
  for (int k = 0; k < T; k += 2) {
    stage(As1, Bs1);                   // tile k+1 in flight across compute
    compute(As0, Bs0);
    __syncthreads();                   // drains vmcnt(0): tile k+1 ready
    if (k + 2 < T) stage(As0, Bs0);    // tile k+2 in flight
    compute(As1, Bs1);
    __syncthreads();
  }

  // epilogue: row = bm*BM + wm + i*16 + (lane>>4)*4 + r, col = bn*BN + wn + j*16 + fr
  if constexpr (EP == 2) {
    float vpart[MI][4];
#pragma unroll
    for (int i = 0; i < MI; ++i)
#pragma unroll
      for (int r = 0; r < 4; ++r) vpart[i][r] = 0.f;
#pragma unroll
    for (int j = 0; j < NJ; ++j) {
      const int col = bn * BN + wn + j * 16 + fr;
      const float bv = bias[col];
      const float w3 = W3[col];
#pragma unroll
      for (int i = 0; i < MI; ++i)
#pragma unroll
        for (int r = 0; r < 4; ++r)
          vpart[i][r] += tanh_fast(acc[i][j][r] + bv) * w3;
    }
    const bool lead = (fr == 0);
    const bool addb = (bn == 0) && ((wave & 1) == 0);
#pragma unroll
    for (int i = 0; i < MI; ++i)
#pragma unroll
      for (int r = 0; r < 4; ++r) {
        float p = vpart[i][r];
        p += __shfl_xor(p, 8);
        p += __shfl_xor(p, 4);
        p += __shfl_xor(p, 2);
        p += __shfl_xor(p, 1);
        if (lead) {
          const int row = bm * BM + wm + i * 16 + (lane >> 4) * 4 + r;
          atomicAdd(vout + row, addb ? p + b3[0] : p);
        }
      }
  } else {
#pragma unroll
    for (int j = 0; j < NJ; ++j) {
      const int col = bn * BN + wn + j * 16 + fr;
      const float bv = bias[col];
#pragma unroll
      for (int i = 0; i < MI; ++i) {
#pragma unroll
        for (int r = 0; r < 4; ++r) {
          const int row = bm * BM + wm + i * 16 + (lane >> 4) * 4 + r;
          const float x = acc[i][j][r] + bv;
          const size_t idx = (size_t)row * N + col;
          if constexpr (EP == 0) {
            outb[idx] = f2bf(tanh_fast(x));
          } else {
            const float att = sigmoid_fast(x);
            outf[idx] = att;
            sa[idx] = f2bf(bf2f(obsb[idx]) * att);
          }
        }
      }
    }
  }
}

extern "C" void kernel_launch(void* const* d_in, const int* in_sizes, int n_in,
                              void* d_out, int out_size, void* d_ws, size_t ws_size,
                              hipStream_t stream) {
  const float* obs   = (const float*)d_in[0];   // [4096,1024]
  const float* We    = (const float*)d_in[1];   // [512,1024]
  const float* be    = (const float*)d_in[2];   // [512]
  const float* attnW = (const float*)d_in[3];   // [1024,512,2]
  const float* attnb = (const float*)d_in[4];   // [1024,2]
  const float* W1    = (const float*)d_in[5];   // [2048,1024]
  const float* b1    = (const float*)d_in[6];   // [2048]
  const float* W2    = (const float*)d_in[7];   // [2048,2048]
  const float* b2    = (const float*)d_in[8];   // [2048]
  const float* W3    = (const float*)d_in[9];   // [1,2048]
  const float* b3    = (const float*)d_in[10];  // [1]
  float* out = (float*)d_out;                   // [4096] v, then [4096,1024] attention

  char* ws = (char*)d_ws;
  u16*   We_b  = (u16*)(ws + 0x00000000);   // 1 MB
  u16*   Wd_b  = (u16*)(ws + 0x00100000);   // 1 MB
  u16*   W1_b  = (u16*)(ws + 0x00200000);   // 4 MB
  u16*   W2_b  = (u16*)(ws + 0x00600000);   // 8 MB
  float* bd    = (float*)(ws + 0x00E00000); // 4 KB
  u16*   obs_b = (u16*)(ws + 0x00E01000);   // 8 MB
  u16*   e_b   = (u16*)(ws + 0x01601000);   // 4 MB
  u16*   sa_b  = (u16*)(ws + 0x01A01000);   // 8 MB
  u16*   h1_b  = (u16*)(ws + 0x02201000);   // 16 MB (end ~50 MB; h2 never stored)

  // prep: all casts + attn weight prep + zero v, one launch
  prep_kernel<<<11264, 256, 0, stream>>>(obs, We, W1, W2, attnW, attnb,
                                         obs_b, We_b, W1_b, W2_b, Wd_b, bd, out);

  // G1: e = tanh(obs @ We^T + be)   [4096,512]  64x64 -> 512 blocks
  gemm_bt<64, 64, 0><<<dim3(64, 8), 256, 0, stream>>>(
      obs_b, We_b, 512, 1024, be, e_b, nullptr, nullptr, nullptr, nullptr, nullptr, nullptr);
  // G2: att = sigmoid(e @ Wd^T + bd); sa = obs*att   [4096,1024]  128x64 -> 512 blocks
  gemm_bt<128, 64, 1><<<dim3(32, 16), 256, 0, stream>>>(
      e_b, Wd_b, 1024, 512, bd, nullptr, out + 4096, obs_b, sa_b, nullptr, nullptr, nullptr);
  // G3: h1 = tanh(sa @ W1^T + b1)   [4096,2048]  128x128 -> 512 blocks
  gemm_bt<128, 128, 0><<<dim3(32, 16), 256, 0, stream>>>(
      sa_b, W1_b, 2048, 1024, b1, h1_b, nullptr, nullptr, nullptr, nullptr, nullptr, nullptr);
  // G4+v: v = tanh(h1 @ W2^T + b2) @ W3 + b3 — fused, h2 never stored
  gemm_bt<128, 128, 2><<<dim3(32, 16), 256, 0, stream>>>(
      h1_b, W2_b, 2048, 2048, b2, nullptr, nullptr, nullptr, nullptr, W3, b3, out);
}